// Round 11
// baseline (152.729 us; speedup 1.0000x reference)
//
#include <hip/hip_runtime.h>
#include <math.h>

typedef _Float16 f16;
typedef _Float16 f16x8 __attribute__((ext_vector_type(8)));
typedef _Float16 f16x4 __attribute__((ext_vector_type(4)));
typedef float f32x4 __attribute__((ext_vector_type(4)));

#define NROWS 12288
#define NFEAT 4096
#define DDIM  256
#define KDIM  1000
#define KPAD  1024
#define NSL0  8     // gemm colsum slabs (depth 12)
#define NSL   32    // rowpass colsum slabs (depth 24)

// workspace layout (bytes)
static const size_t OFF_A16 = 0;           // 12288*256 f16 = 6,291,456
static const size_t OFF_BF  = 6291456;     // 1024*256 f16  =   524,288
static const size_t OFF_E16 = 6815744;     // 12288*1024 f16= 25,165,824
static const size_t OFF_SL  = 31981568;    // (8+32+32)*1024 f32 = 294,912

__device__ inline float wsum(float v) {
#pragma unroll
    for (int m = 32; m >= 1; m >>= 1) v += __shfl_xor(v, m, 64);
    return v;
}

// ---------------------------------------------------------------------------
// prep: [0,3072)   feats/queue row norms -> A16 (4 rows/block)
//       [3072,3104) head: 8 k-rows/block -> transposed normalized f16 Bf
//       [3104,3176) zero slab accumulators (72 KPAD-rows of f32)
__global__ __launch_bounds__(256)
void prep_k(const float* __restrict__ feats, const float* __restrict__ queue,
            const float* __restrict__ head, f16* __restrict__ A16,
            f16* __restrict__ Bf, float* __restrict__ slabs) {
    int b = blockIdx.x, tid = threadIdx.x;
    int wave = tid >> 6, lane = tid & 63;
    if (b < 3072) {
        int row = b * 4 + wave;
        const float* src = (row < NFEAT) ? feats + (size_t)row * DDIM
                                         : queue + (size_t)(row - NFEAT) * DDIM;
        float4 v = *(const float4*)(src + lane * 4);
        float s = wsum(v.x * v.x + v.y * v.y + v.z * v.z + v.w * v.w);
        float inv = 1.0f / sqrtf(fmaxf(s, 1e-24f));
        f16x4 o = { (f16)(v.x * inv), (f16)(v.y * inv), (f16)(v.z * inv), (f16)(v.w * inv) };
        *(f16x4*)(A16 + (size_t)row * DDIM + lane * 4) = o;
    } else if (b < 3104) {
        __shared__ float rin[8];
        int kb = (b - 3072) * 8;
        for (int j = 0; j < 2; ++j) {
            int k = kb + wave * 2 + j;
            const float* hr = head + (size_t)k * KDIM;
            float s = 0.f;
            for (int n = lane; n < KDIM; n += 64) { float v = hr[n]; s += v * v; }
            s = wsum(s);
            if (lane == 0) rin[wave * 2 + j] = 1.0f / sqrtf(fmaxf(s, 1e-24f));
        }
        __syncthreads();
        float r[8];
#pragma unroll
        for (int i = 0; i < 8; ++i) r[i] = rin[i];
        for (int n = tid; n < KDIM; n += 256) {
            f16 tmp[8];
#pragma unroll
            for (int i = 0; i < 8; ++i)
                tmp[i] = (f16)(head[(size_t)(kb + i) * KDIM + n] * r[i]);
            *(uint4*)(Bf + (size_t)n * DDIM + kb) = *(const uint4*)(tmp);
        }
    } else {
        float* dst = slabs + (size_t)(b - 3104) * KPAD + tid * 4;
        *(float4*)dst = make_float4(0.f, 0.f, 0.f, 0.f);
    }
}

// ---------------------------------------------------------------------------
// MFMA GEMM (register double-buffered K-loop) + exp + f16 E store;
// LDS-combined colsum partial -> relaxed atomicAdd into S0 slab (by & 7).
__global__ __launch_bounds__(256, 3)
void gemm_exp_k(const f16* __restrict__ A16, const f16* __restrict__ Bf,
                f16* __restrict__ E16, float* __restrict__ S0sl) {
    __shared__ __align__(16) char smem[34816];
    f16 (*Es)[136] = (f16(*)[136])smem;
    int tid = threadIdx.x;
    int wave = tid >> 6, lane = tid & 63;
    int lm = lane & 15, q = lane >> 4;
    int row0 = blockIdx.y * 128, col0 = blockIdx.x * 128;
    int wm = (wave >> 1) * 64, wn = (wave & 1) * 64;
    const f16* Ab = A16 + (size_t)(row0 + wm + lm) * DDIM + q * 8;
    const f16* Bb = Bf  + (size_t)(col0 + wn + lm) * DDIM + q * 8;

    f32x4 acc[4][4];
#pragma unroll
    for (int i = 0; i < 4; ++i)
#pragma unroll
        for (int j = 0; j < 4; ++j) acc[i][j] = (f32x4){0.f, 0.f, 0.f, 0.f};

    f16x8 ca[4], cb[4], na[4], nb[4];
#pragma unroll
    for (int ms = 0; ms < 4; ++ms) ca[ms] = *(const f16x8*)(Ab + (size_t)ms * 16 * DDIM);
#pragma unroll
    for (int ns = 0; ns < 4; ++ns) cb[ns] = *(const f16x8*)(Bb + (size_t)ns * 16 * DDIM);

#pragma unroll
    for (int kt = 0; kt < DDIM; kt += 32) {
        if (kt + 32 < DDIM) {
#pragma unroll
            for (int ms = 0; ms < 4; ++ms)
                na[ms] = *(const f16x8*)(Ab + (size_t)ms * 16 * DDIM + kt + 32);
#pragma unroll
            for (int ns = 0; ns < 4; ++ns)
                nb[ns] = *(const f16x8*)(Bb + (size_t)ns * 16 * DDIM + kt + 32);
        }
#pragma unroll
        for (int ms = 0; ms < 4; ++ms)
#pragma unroll
            for (int ns = 0; ns < 4; ++ns)
                acc[ms][ns] = __builtin_amdgcn_mfma_f32_16x16x32_f16(ca[ms], cb[ns], acc[ms][ns], 0, 0, 0);
#pragma unroll
        for (int ms = 0; ms < 4; ++ms) ca[ms] = na[ms];
#pragma unroll
        for (int ns = 0; ns < 4; ++ns) cb[ns] = nb[ns];
    }

    float colp[4] = {0.f, 0.f, 0.f, 0.f};
#pragma unroll
    for (int ms = 0; ms < 4; ++ms) {
#pragma unroll
        for (int ns = 0; ns < 4; ++ns) {
            int gc = col0 + wn + ns * 16 + lm;
            bool ok = gc < KDIM;
#pragma unroll
            for (int r = 0; r < 4; ++r) {
                float e = ok ? __expf(acc[ms][ns][r] * 20.0f) : 0.0f;
                colp[ns] += e;
                Es[wm + ms * 16 + q * 4 + r][wn + ns * 16 + lm] = (f16)e;
            }
        }
    }
#pragma unroll
    for (int ns = 0; ns < 4; ++ns) {
        colp[ns] += __shfl_xor(colp[ns], 16, 64);
        colp[ns] += __shfl_xor(colp[ns], 32, 64);
    }
    __syncthreads();
    {
        int r = tid >> 1, half = tid & 1;
        const f16* src = &Es[r][half * 64];
        f16* dst = E16 + (size_t)(row0 + r) * KPAD + col0 + half * 64;
#pragma unroll
        for (int i = 0; i < 8; ++i)
            *(uint4*)(dst + i * 8) = *(const uint4*)(src + i * 8);
    }
    __syncthreads();
    float* cred = (float*)smem;
    if (tid < 128) cred[tid] = 0.f;
    __syncthreads();
    if (lane < 16) {
#pragma unroll
        for (int ns = 0; ns < 4; ++ns)
            atomicAdd(&cred[wn + ns * 16 + lane], colp[ns]);
    }
    __syncthreads();
    if (tid < 128)
        atomicAdd(&S0sl[(size_t)(blockIdx.y & (NSL0 - 1)) * KPAD + col0 + tid], cred[tid]);
}

// ---------------------------------------------------------------------------
// rowpass: prologue folds NSIN-slab reduce of Sin -> rl; per-row
// c[b]=1/(12288*dot(E[b,:],r)); LDS-combined colsum partial -> relaxed
// atomicAdd into Sout slab (bid & 31). 768 blocks x 16 rows.
template <int NSIN>
__global__ __launch_bounds__(256)
void rowpass_k(const f16* __restrict__ E16, const float* __restrict__ SinSl,
               float* __restrict__ SoutSl) {
    __shared__ float rl[KPAD];
    __shared__ float cols4[4][KPAD];
    int tid = threadIdx.x, bid = blockIdx.x;
    for (int n = tid; n < KPAD; n += 256) {
        float s = 0.f;
#pragma unroll
        for (int j = 0; j < NSIN; ++j) s += SinSl[(size_t)j * KPAD + n];
        rl[n] = (n < KDIM) ? 1.0f / (1000.0f * s) : 0.0f;
    }
    __syncthreads();
    int wave = tid >> 6, lane = tid & 63;
    int n0 = lane * 16;
    float rv[16];
#pragma unroll
    for (int i = 0; i < 16; ++i) rv[i] = rl[n0 + i];
    float ca[16];
#pragma unroll
    for (int i = 0; i < 16; ++i) ca[i] = 0.f;
    int rowbase = bid * 16 + wave * 4;
#pragma unroll
    for (int j = 0; j < 4; ++j) {
        const f16* er = E16 + (size_t)(rowbase + j) * KPAD + n0;
        f16x8 e0 = *(const f16x8*)er;
        f16x8 e1 = *(const f16x8*)(er + 8);
        float ev[16];
#pragma unroll
        for (int i = 0; i < 8; ++i) { ev[i] = (float)e0[i]; ev[8 + i] = (float)e1[i]; }
        float p = 0.f;
#pragma unroll
        for (int i = 0; i < 16; ++i) p += ev[i] * rv[i];
        p = wsum(p);
        float c = 1.0f / (12288.0f * p);
#pragma unroll
        for (int i = 0; i < 16; ++i) ca[i] += ev[i] * c;
    }
#pragma unroll
    for (int i = 0; i < 16; ++i) {
        int idx = (i + lane) & 15;
        cols4[wave][n0 + idx] = ca[idx];
    }
    __syncthreads();
    float* outSlab = SoutSl + (size_t)(bid & (NSL - 1)) * KPAD;
    for (int n = tid; n < KPAD; n += 256)
        atomicAdd(&outSlab[n],
                  cols4[0][n] + cols4[1][n] + cols4[2][n] + cols4[3][n]);
}

// ---------------------------------------------------------------------------
// out: prologue folds 32-slab reduce of S2; out[b,:] = E[b,:]*r / rowsum.
// 1024 blocks, 1 row per wave, rows < 4096.
__global__ __launch_bounds__(256)
void out_k(const f16* __restrict__ E16, const float* __restrict__ S2sl,
           float* __restrict__ out) {
    __shared__ float rl[KPAD];
    int tid = threadIdx.x;
    for (int n = tid; n < KPAD; n += 256) {
        float s = 0.f;
#pragma unroll
        for (int j = 0; j < NSL; ++j) s += S2sl[(size_t)j * KPAD + n];
        rl[n] = (n < KDIM) ? 1.0f / (1000.0f * s) : 0.0f;
    }
    __syncthreads();
    int wave = tid >> 6, lane = tid & 63;
    int n0 = lane * 16;
    float rv[16];
#pragma unroll
    for (int i = 0; i < 16; ++i) rv[i] = rl[n0 + i];
    int row = blockIdx.x * 4 + wave;
    const f16* er = E16 + (size_t)row * KPAD + n0;
    f16x8 e0 = *(const f16x8*)er;
    f16x8 e1 = *(const f16x8*)(er + 8);
    float w[16];
    float p = 0.f;
#pragma unroll
    for (int i = 0; i < 8; ++i) {
        w[i] = (float)e0[i] * rv[i];
        w[8 + i] = (float)e1[i] * rv[8 + i];
    }
#pragma unroll
    for (int i = 0; i < 16; ++i) p += w[i];
    p = wsum(p);
    float inv = 1.0f / p;
    float* orow = out + (size_t)row * KDIM;
#pragma unroll
    for (int i = 0; i < 16; i += 4) {
        int n = n0 + i;
        if (n + 3 < KDIM) {
            float4 o = { w[i] * inv, w[i + 1] * inv, w[i + 2] * inv, w[i + 3] * inv };
            *(float4*)(orow + n) = o;
        } else {
#pragma unroll
            for (int t = 0; t < 4; ++t)
                if (n + t < KDIM) orow[n + t] = w[i + t] * inv;
        }
    }
}

// ---------------------------------------------------------------------------
extern "C" void kernel_launch(void* const* d_in, const int* in_sizes, int n_in,
                              void* d_out, int out_size, void* d_ws, size_t ws_size,
                              hipStream_t stream) {
    (void)in_sizes; (void)n_in; (void)out_size; (void)ws_size;
    const float* feats = (const float*)d_in[0];   // [4096,256]
    const float* head  = (const float*)d_in[1];   // [256,1000]
    const float* queue = (const float*)d_in[2];   // [8192,256]
    float* out = (float*)d_out;                   // [4096,1000]

    char* ws = (char*)d_ws;
    f16*   A16   = (f16*)(ws + OFF_A16);
    f16*   Bf    = (f16*)(ws + OFF_BF);
    f16*   E16   = (f16*)(ws + OFF_E16);
    float* slabs = (float*)(ws + OFF_SL);
    float* S0sl  = slabs;                         // 8 rows
    float* S1sl  = slabs + NSL0 * KPAD;           // 32 rows
    float* S2sl  = S1sl + NSL * KPAD;             // 32 rows

    prep_k<<<3176, 256, 0, stream>>>(feats, queue, head, A16, Bf, slabs);
    gemm_exp_k<<<dim3(8, 96), 256, 0, stream>>>(A16, Bf, E16, S0sl);
    rowpass_k<NSL0><<<768, 256, 0, stream>>>(E16, S0sl, S1sl);
    rowpass_k<NSL><<<768, 256, 0, stream>>>(E16, S1sl, S2sl);
    out_k<<<NFEAT / 4, 256, 0, stream>>>(E16, S2sl, out);
}

// Round 12
// 145.241 us; speedup vs baseline: 1.0516x; 1.0516x over previous
//
#include <hip/hip_runtime.h>
#include <math.h>

typedef _Float16 f16;
typedef _Float16 f16x8 __attribute__((ext_vector_type(8)));
typedef _Float16 f16x4 __attribute__((ext_vector_type(4)));
typedef float f32x4 __attribute__((ext_vector_type(4)));

#define NROWS 12288
#define NFEAT 4096
#define DDIM  256
#define KDIM  1000
#define KPAD  1024
#define NSLAB 8

// workspace layout (bytes)
static const size_t OFF_A16 = 0;           // 12288*256 f16 = 6,291,456
static const size_t OFF_BF  = 6291456;     // 1024*256 f16  =   524,288
static const size_t OFF_E16 = 6815744;     // 12288*1024 f16= 25,165,824
static const size_t OFF_SL  = 31981568;    // 3 * 8 * 1024 f32 slabs

__device__ inline float wsum(float v) {
#pragma unroll
    for (int m = 32; m >= 1; m >>= 1) v += __shfl_xor(v, m, 64);
    return v;
}

// ---------------------------------------------------------------------------
// prep: [0,3072)   feats/queue row norms -> A16 (4 rows/block)
//       [3072,3104) head: 8 k-rows/block -> transposed normalized f16 Bf
//       [3104,3128) zero the 3 slab accumulators
__global__ __launch_bounds__(256)
void prep_k(const float* __restrict__ feats, const float* __restrict__ queue,
            const float* __restrict__ head, f16* __restrict__ A16,
            f16* __restrict__ Bf, float* __restrict__ slabs) {
    int b = blockIdx.x, tid = threadIdx.x;
    int wave = tid >> 6, lane = tid & 63;
    if (b < 3072) {
        int row = b * 4 + wave;
        const float* src = (row < NFEAT) ? feats + (size_t)row * DDIM
                                         : queue + (size_t)(row - NFEAT) * DDIM;
        float4 v = *(const float4*)(src + lane * 4);
        float s = wsum(v.x * v.x + v.y * v.y + v.z * v.z + v.w * v.w);
        float inv = 1.0f / sqrtf(fmaxf(s, 1e-24f));
        f16x4 o = { (f16)(v.x * inv), (f16)(v.y * inv), (f16)(v.z * inv), (f16)(v.w * inv) };
        *(f16x4*)(A16 + (size_t)row * DDIM + lane * 4) = o;
    } else if (b < 3104) {
        __shared__ float rin[8];
        int kb = (b - 3072) * 8;
        for (int j = 0; j < 2; ++j) {
            int k = kb + wave * 2 + j;
            const float* hr = head + (size_t)k * KDIM;
            float s = 0.f;
            for (int n = lane; n < KDIM; n += 64) { float v = hr[n]; s += v * v; }
            s = wsum(s);
            if (lane == 0) rin[wave * 2 + j] = 1.0f / sqrtf(fmaxf(s, 1e-24f));
        }
        __syncthreads();
        float r[8];
#pragma unroll
        for (int i = 0; i < 8; ++i) r[i] = rin[i];
        for (int n = tid; n < KDIM; n += 256) {
            f16 tmp[8];
#pragma unroll
            for (int i = 0; i < 8; ++i)
                tmp[i] = (f16)(head[(size_t)(kb + i) * KDIM + n] * r[i]);
            *(uint4*)(Bf + (size_t)n * DDIM + kb) = *(const uint4*)(tmp);
        }
    } else {
        float* dst = slabs + (size_t)(b - 3104) * KPAD + tid * 4;
        *(float4*)dst = make_float4(0.f, 0.f, 0.f, 0.f);
    }
}

// ---------------------------------------------------------------------------
// MFMA GEMM + exp + f16 E store; LDS-combined colsum partial -> relaxed
// atomicAdd into S0 slab (blockIdx.y & 7).  (R10 version — R11's manual
// register double-buffer regressed: 64 v_movs/iter vs compiler schedule.)
__global__ __launch_bounds__(256, 3)
void gemm_exp_k(const f16* __restrict__ A16, const f16* __restrict__ Bf,
                f16* __restrict__ E16, float* __restrict__ S0sl) {
    __shared__ __align__(16) char smem[34816];
    f16 (*Es)[136] = (f16(*)[136])smem;
    int tid = threadIdx.x;
    int wave = tid >> 6, lane = tid & 63;
    int lm = lane & 15, q = lane >> 4;
    int row0 = blockIdx.y * 128, col0 = blockIdx.x * 128;
    int wm = (wave >> 1) * 64, wn = (wave & 1) * 64;
    const f16* Ab = A16 + (size_t)(row0 + wm + lm) * DDIM + q * 8;
    const f16* Bb = Bf  + (size_t)(col0 + wn + lm) * DDIM + q * 8;

    f32x4 acc[4][4];
#pragma unroll
    for (int i = 0; i < 4; ++i)
#pragma unroll
        for (int j = 0; j < 4; ++j) acc[i][j] = (f32x4){0.f, 0.f, 0.f, 0.f};

#pragma unroll
    for (int kt = 0; kt < DDIM; kt += 32) {
        f16x8 a[4], b[4];
#pragma unroll
        for (int ms = 0; ms < 4; ++ms) a[ms] = *(const f16x8*)(Ab + (size_t)ms * 16 * DDIM + kt);
#pragma unroll
        for (int ns = 0; ns < 4; ++ns) b[ns] = *(const f16x8*)(Bb + (size_t)ns * 16 * DDIM + kt);
#pragma unroll
        for (int ms = 0; ms < 4; ++ms)
#pragma unroll
            for (int ns = 0; ns < 4; ++ns)
                acc[ms][ns] = __builtin_amdgcn_mfma_f32_16x16x32_f16(a[ms], b[ns], acc[ms][ns], 0, 0, 0);
    }

    float colp[4] = {0.f, 0.f, 0.f, 0.f};
#pragma unroll
    for (int ms = 0; ms < 4; ++ms) {
#pragma unroll
        for (int ns = 0; ns < 4; ++ns) {
            int gc = col0 + wn + ns * 16 + lm;
            bool ok = gc < KDIM;
#pragma unroll
            for (int r = 0; r < 4; ++r) {
                float e = ok ? __expf(acc[ms][ns][r] * 20.0f) : 0.0f;
                colp[ns] += e;
                Es[wm + ms * 16 + q * 4 + r][wn + ns * 16 + lm] = (f16)e;
            }
        }
    }
#pragma unroll
    for (int ns = 0; ns < 4; ++ns) {
        colp[ns] += __shfl_xor(colp[ns], 16, 64);
        colp[ns] += __shfl_xor(colp[ns], 32, 64);
    }
    __syncthreads();
    {
        int r = tid >> 1, half = tid & 1;
        const f16* src = &Es[r][half * 64];
        f16* dst = E16 + (size_t)(row0 + r) * KPAD + col0 + half * 64;
#pragma unroll
        for (int i = 0; i < 8; ++i)
            *(uint4*)(dst + i * 8) = *(const uint4*)(src + i * 8);
    }
    __syncthreads();
    float* cred = (float*)smem;
    if (tid < 128) cred[tid] = 0.f;
    __syncthreads();
    if (lane < 16) {
#pragma unroll
        for (int ns = 0; ns < 4; ++ns)
            atomicAdd(&cred[wn + ns * 16 + lane], colp[ns]);   // LDS atomic
    }
    __syncthreads();
    if (tid < 128)
        atomicAdd(&S0sl[(size_t)(blockIdx.y & 7) * KPAD + col0 + tid], cred[tid]);
}

// ---------------------------------------------------------------------------
// rowpass: prologue folds 8-slab reduce of Sin -> rl; per-row
// c[b]=1/(12288*dot(E[b,:],r)); LDS-combined colsum partial -> relaxed
// atomicAdd into Sout slab (bid & 7), sweep PHASE-ROTATED by (bid>>3)&3 so
// in-flight blocks spread over the 4 KB slab instead of marching in lockstep.
__global__ __launch_bounds__(256)
void rowpass_k(const f16* __restrict__ E16, const float* __restrict__ SinSl,
               float* __restrict__ SoutSl) {
    __shared__ float rl[KPAD];
    __shared__ float cols4[4][KPAD];
    int tid = threadIdx.x, bid = blockIdx.x;
    for (int n = tid; n < KPAD; n += 256) {
        float s = 0.f;
#pragma unroll
        for (int j = 0; j < NSLAB; ++j) s += SinSl[(size_t)j * KPAD + n];
        rl[n] = (n < KDIM) ? 1.0f / (1000.0f * s) : 0.0f;
    }
    __syncthreads();
    int wave = tid >> 6, lane = tid & 63;
    int n0 = lane * 16;
    float rv[16];
#pragma unroll
    for (int i = 0; i < 16; ++i) rv[i] = rl[n0 + i];
    float ca[16];
#pragma unroll
    for (int i = 0; i < 16; ++i) ca[i] = 0.f;
    int rowbase = bid * 16 + wave * 4;
#pragma unroll
    for (int j = 0; j < 4; ++j) {
        const f16* er = E16 + (size_t)(rowbase + j) * KPAD + n0;
        f16x8 e0 = *(const f16x8*)er;
        f16x8 e1 = *(const f16x8*)(er + 8);
        float ev[16];
#pragma unroll
        for (int i = 0; i < 8; ++i) { ev[i] = (float)e0[i]; ev[8 + i] = (float)e1[i]; }
        float p = 0.f;
#pragma unroll
        for (int i = 0; i < 16; ++i) p += ev[i] * rv[i];
        p = wsum(p);
        float c = 1.0f / (12288.0f * p);
#pragma unroll
        for (int i = 0; i < 16; ++i) ca[i] += ev[i] * c;
    }
#pragma unroll
    for (int i = 0; i < 16; ++i) {
        int idx = (i + lane) & 15;
        cols4[wave][n0 + idx] = ca[idx];
    }
    __syncthreads();
    float* outSlab = SoutSl + (size_t)(bid & 7) * KPAD;
    int phase = (bid >> 3) & 3;
#pragma unroll
    for (int jj = 0; jj < 4; ++jj) {
        int n = ((jj + phase) & 3) * 256 + tid;
        atomicAdd(&outSlab[n],
                  cols4[0][n] + cols4[1][n] + cols4[2][n] + cols4[3][n]);
    }
}

// ---------------------------------------------------------------------------
// out: prologue folds 8-slab reduce of S2; out[b,:] = E[b,:]*r / rowsum.
// 1024 blocks, 1 row per wave, rows < 4096.
__global__ __launch_bounds__(256)
void out_k(const f16* __restrict__ E16, const float* __restrict__ S2sl,
           float* __restrict__ out) {
    __shared__ float rl[KPAD];
    int tid = threadIdx.x;
    for (int n = tid; n < KPAD; n += 256) {
        float s = 0.f;
#pragma unroll
        for (int j = 0; j < NSLAB; ++j) s += S2sl[(size_t)j * KPAD + n];
        rl[n] = (n < KDIM) ? 1.0f / (1000.0f * s) : 0.0f;
    }
    __syncthreads();
    int wave = tid >> 6, lane = tid & 63;
    int n0 = lane * 16;
    float rv[16];
#pragma unroll
    for (int i = 0; i < 16; ++i) rv[i] = rl[n0 + i];
    int row = blockIdx.x * 4 + wave;
    const f16* er = E16 + (size_t)row * KPAD + n0;
    f16x8 e0 = *(const f16x8*)er;
    f16x8 e1 = *(const f16x8*)(er + 8);
    float w[16];
    float p = 0.f;
#pragma unroll
    for (int i = 0; i < 8; ++i) {
        w[i] = (float)e0[i] * rv[i];
        w[8 + i] = (float)e1[i] * rv[8 + i];
    }
#pragma unroll
    for (int i = 0; i < 16; ++i) p += w[i];
    p = wsum(p);
    float inv = 1.0f / p;
    float* orow = out + (size_t)row * KDIM;
#pragma unroll
    for (int i = 0; i < 16; i += 4) {
        int n = n0 + i;
        if (n + 3 < KDIM) {
            float4 o = { w[i] * inv, w[i + 1] * inv, w[i + 2] * inv, w[i + 3] * inv };
            *(float4*)(orow + n) = o;
        } else {
#pragma unroll
            for (int t = 0; t < 4; ++t)
                if (n + t < KDIM) orow[n + t] = w[i + t] * inv;
        }
    }
}

// ---------------------------------------------------------------------------
extern "C" void kernel_launch(void* const* d_in, const int* in_sizes, int n_in,
                              void* d_out, int out_size, void* d_ws, size_t ws_size,
                              hipStream_t stream) {
    (void)in_sizes; (void)n_in; (void)out_size; (void)ws_size;
    const float* feats = (const float*)d_in[0];   // [4096,256]
    const float* head  = (const float*)d_in[1];   // [256,1000]
    const float* queue = (const float*)d_in[2];   // [8192,256]
    float* out = (float*)d_out;                   // [4096,1000]

    char* ws = (char*)d_ws;
    f16*   A16   = (f16*)(ws + OFF_A16);
    f16*   Bf    = (f16*)(ws + OFF_BF);
    f16*   E16   = (f16*)(ws + OFF_E16);
    float* slabs = (float*)(ws + OFF_SL);
    float* S0sl  = slabs;
    float* S1sl  = slabs + NSLAB * KPAD;
    float* S2sl  = slabs + 2 * NSLAB * KPAD;

    prep_k<<<3128, 256, 0, stream>>>(feats, queue, head, A16, Bf, slabs);
    gemm_exp_k<<<dim3(8, 96), 256, 0, stream>>>(A16, Bf, E16, S0sl);
    rowpass_k<<<768, 256, 0, stream>>>(E16, S0sl, S1sl);
    rowpass_k<<<768, 256, 0, stream>>>(E16, S1sl, S2sl);
    out_k<<<NFEAT / 4, 256, 0, stream>>>(E16, S2sl, out);
}

// Round 13
// 143.971 us; speedup vs baseline: 1.0608x; 1.0088x over previous
//
#include <hip/hip_runtime.h>
#include <math.h>

typedef _Float16 f16;
typedef _Float16 f16x8 __attribute__((ext_vector_type(8)));
typedef _Float16 f16x4 __attribute__((ext_vector_type(4)));
typedef float f32x4 __attribute__((ext_vector_type(4)));

#define NROWS 12288
#define NFEAT 4096
#define DDIM  256
#define KDIM  1000
#define KPAD  1024
#define NSLAB 8

// workspace layout (bytes)
static const size_t OFF_A16 = 0;           // 12288*256 f16 = 6,291,456
static const size_t OFF_BF  = 6291456;     // 1024*256 f16  =   524,288
static const size_t OFF_E16 = 6815744;     // 12288*1024 f16= 25,165,824
static const size_t OFF_SL  = 31981568;    // 3 * 8 * 1024 f32 slabs

__device__ inline float wsum(float v) {
#pragma unroll
    for (int m = 32; m >= 1; m >>= 1) v += __shfl_xor(v, m, 64);
    return v;
}

// ---------------------------------------------------------------------------
// prep: [0,3072)   feats/queue row norms -> A16 (4 rows/block)
//       [3072,3104) head: 8 k-rows/block -> transposed normalized f16 Bf
//       [3104,3128) zero the 3 slab accumulators
__global__ __launch_bounds__(256)
void prep_k(const float* __restrict__ feats, const float* __restrict__ queue,
            const float* __restrict__ head, f16* __restrict__ A16,
            f16* __restrict__ Bf, float* __restrict__ slabs) {
    int b = blockIdx.x, tid = threadIdx.x;
    int wave = tid >> 6, lane = tid & 63;
    if (b < 3072) {
        int row = b * 4 + wave;
        const float* src = (row < NFEAT) ? feats + (size_t)row * DDIM
                                         : queue + (size_t)(row - NFEAT) * DDIM;
        float4 v = *(const float4*)(src + lane * 4);
        float s = wsum(v.x * v.x + v.y * v.y + v.z * v.z + v.w * v.w);
        float inv = 1.0f / sqrtf(fmaxf(s, 1e-24f));
        f16x4 o = { (f16)(v.x * inv), (f16)(v.y * inv), (f16)(v.z * inv), (f16)(v.w * inv) };
        *(f16x4*)(A16 + (size_t)row * DDIM + lane * 4) = o;
    } else if (b < 3104) {
        __shared__ float rin[8];
        int kb = (b - 3072) * 8;
        for (int j = 0; j < 2; ++j) {
            int k = kb + wave * 2 + j;
            const float* hr = head + (size_t)k * KDIM;
            float s = 0.f;
            for (int n = lane; n < KDIM; n += 64) { float v = hr[n]; s += v * v; }
            s = wsum(s);
            if (lane == 0) rin[wave * 2 + j] = 1.0f / sqrtf(fmaxf(s, 1e-24f));
        }
        __syncthreads();
        float r[8];
#pragma unroll
        for (int i = 0; i < 8; ++i) r[i] = rin[i];
        for (int n = tid; n < KDIM; n += 256) {
            f16 tmp[8];
#pragma unroll
            for (int i = 0; i < 8; ++i)
                tmp[i] = (f16)(head[(size_t)(kb + i) * KDIM + n] * r[i]);
            *(uint4*)(Bf + (size_t)n * DDIM + kb) = *(const uint4*)(tmp);
        }
    } else {
        float* dst = slabs + (size_t)(b - 3104) * KPAD + tid * 4;
        *(float4*)dst = make_float4(0.f, 0.f, 0.f, 0.f);
    }
}

// ---------------------------------------------------------------------------
// MFMA GEMM + exp + f16 E store; LDS-combined colsum partial -> relaxed
// atomicAdd into S0 slab (blockIdx.y & 7).  (R10 structure, untouched.)
__global__ __launch_bounds__(256, 3)
void gemm_exp_k(const f16* __restrict__ A16, const f16* __restrict__ Bf,
                f16* __restrict__ E16, float* __restrict__ S0sl) {
    __shared__ __align__(16) char smem[34816];
    f16 (*Es)[136] = (f16(*)[136])smem;
    int tid = threadIdx.x;
    int wave = tid >> 6, lane = tid & 63;
    int lm = lane & 15, q = lane >> 4;
    int row0 = blockIdx.y * 128, col0 = blockIdx.x * 128;
    int wm = (wave >> 1) * 64, wn = (wave & 1) * 64;
    const f16* Ab = A16 + (size_t)(row0 + wm + lm) * DDIM + q * 8;
    const f16* Bb = Bf  + (size_t)(col0 + wn + lm) * DDIM + q * 8;

    f32x4 acc[4][4];
#pragma unroll
    for (int i = 0; i < 4; ++i)
#pragma unroll
        for (int j = 0; j < 4; ++j) acc[i][j] = (f32x4){0.f, 0.f, 0.f, 0.f};

#pragma unroll
    for (int kt = 0; kt < DDIM; kt += 32) {
        f16x8 a[4], b[4];
#pragma unroll
        for (int ms = 0; ms < 4; ++ms) a[ms] = *(const f16x8*)(Ab + (size_t)ms * 16 * DDIM + kt);
#pragma unroll
        for (int ns = 0; ns < 4; ++ns) b[ns] = *(const f16x8*)(Bb + (size_t)ns * 16 * DDIM + kt);
#pragma unroll
        for (int ms = 0; ms < 4; ++ms)
#pragma unroll
            for (int ns = 0; ns < 4; ++ns)
                acc[ms][ns] = __builtin_amdgcn_mfma_f32_16x16x32_f16(a[ms], b[ns], acc[ms][ns], 0, 0, 0);
    }

    float colp[4] = {0.f, 0.f, 0.f, 0.f};
#pragma unroll
    for (int ms = 0; ms < 4; ++ms) {
#pragma unroll
        for (int ns = 0; ns < 4; ++ns) {
            int gc = col0 + wn + ns * 16 + lm;
            bool ok = gc < KDIM;
#pragma unroll
            for (int r = 0; r < 4; ++r) {
                float e = ok ? __expf(acc[ms][ns][r] * 20.0f) : 0.0f;
                colp[ns] += e;
                Es[wm + ms * 16 + q * 4 + r][wn + ns * 16 + lm] = (f16)e;
            }
        }
    }
#pragma unroll
    for (int ns = 0; ns < 4; ++ns) {
        colp[ns] += __shfl_xor(colp[ns], 16, 64);
        colp[ns] += __shfl_xor(colp[ns], 32, 64);
    }
    __syncthreads();
    {
        int r = tid >> 1, half = tid & 1;
        const f16* src = &Es[r][half * 64];
        f16* dst = E16 + (size_t)(row0 + r) * KPAD + col0 + half * 64;
#pragma unroll
        for (int i = 0; i < 8; ++i)
            *(uint4*)(dst + i * 8) = *(const uint4*)(src + i * 8);
    }
    __syncthreads();
    float* cred = (float*)smem;
    if (tid < 128) cred[tid] = 0.f;
    __syncthreads();
    if (lane < 16) {
#pragma unroll
        for (int ns = 0; ns < 4; ++ns)
            atomicAdd(&cred[wn + ns * 16 + lane], colp[ns]);   // LDS atomic
    }
    __syncthreads();
    if (tid < 128)
        atomicAdd(&S0sl[(size_t)(blockIdx.y & 7) * KPAD + col0 + tid], cred[tid]);
}

// ---------------------------------------------------------------------------
// rowpass, ILP version: load all 4 rows up front, 4 independent dot chains,
// INTERLEAVED 6-stage butterflies (pipelined, ~1/3 the serial latency),
// then accumulate. Prologue slab reduce vectorized with float4.
__global__ __launch_bounds__(256)
void rowpass_k(const f16* __restrict__ E16, const float* __restrict__ SinSl,
               float* __restrict__ SoutSl) {
    __shared__ float rl[KPAD];
    __shared__ float cols4[4][KPAD];
    int tid = threadIdx.x, bid = blockIdx.x;
    {
        int n = tid * 4;                       // 256 threads x float4 = KPAD
        float4 s = *(const float4*)(SinSl + n);
#pragma unroll
        for (int j = 1; j < NSLAB; ++j) {
            float4 t = *(const float4*)(SinSl + (size_t)j * KPAD + n);
            s.x += t.x; s.y += t.y; s.z += t.z; s.w += t.w;
        }
        float4 o;
        o.x = (n + 0 < KDIM) ? 1.0f / (1000.0f * s.x) : 0.0f;
        o.y = (n + 1 < KDIM) ? 1.0f / (1000.0f * s.y) : 0.0f;
        o.z = (n + 2 < KDIM) ? 1.0f / (1000.0f * s.z) : 0.0f;
        o.w = (n + 3 < KDIM) ? 1.0f / (1000.0f * s.w) : 0.0f;
        *(float4*)(rl + n) = o;
    }
    __syncthreads();
    int wave = tid >> 6, lane = tid & 63;
    int n0 = lane * 16;
    float rv[16];
#pragma unroll
    for (int i = 0; i < 16; ++i) rv[i] = rl[n0 + i];

    int rowbase = bid * 16 + wave * 4;
    const f16* erb = E16 + (size_t)rowbase * KPAD + n0;
    // load all 4 rows (8 independent 16B loads)
    f16x8 e[4][2];
#pragma unroll
    for (int j = 0; j < 4; ++j) {
        e[j][0] = *(const f16x8*)(erb + (size_t)j * KPAD);
        e[j][1] = *(const f16x8*)(erb + (size_t)j * KPAD + 8);
    }
    // 4 independent dot chains
    float p[4];
#pragma unroll
    for (int j = 0; j < 4; ++j) {
        float acc = 0.f;
#pragma unroll
        for (int i = 0; i < 8; ++i) {
            acc += (float)e[j][0][i] * rv[i];
            acc += (float)e[j][1][i] * rv[8 + i];
        }
        p[j] = acc;
    }
    // interleaved butterflies: 6 stages, 4 chains pipelined per stage
#pragma unroll
    for (int m = 32; m >= 1; m >>= 1) {
        float t0 = __shfl_xor(p[0], m, 64);
        float t1 = __shfl_xor(p[1], m, 64);
        float t2 = __shfl_xor(p[2], m, 64);
        float t3 = __shfl_xor(p[3], m, 64);
        p[0] += t0; p[1] += t1; p[2] += t2; p[3] += t3;
    }
    float c[4];
#pragma unroll
    for (int j = 0; j < 4; ++j) c[j] = 1.0f / (12288.0f * p[j]);
    // accumulate column partials
    float ca[16];
#pragma unroll
    for (int i = 0; i < 16; ++i) {
        int h = i >> 3, ii = i & 7;
        ca[i] = (float)e[0][h][ii] * c[0] + (float)e[1][h][ii] * c[1]
              + (float)e[2][h][ii] * c[2] + (float)e[3][h][ii] * c[3];
    }
#pragma unroll
    for (int i = 0; i < 16; ++i) {
        int idx = (i + lane) & 15;
        cols4[wave][n0 + idx] = ca[idx];
    }
    __syncthreads();
    float* outSlab = SoutSl + (size_t)(bid & 7) * KPAD;
    for (int n = tid; n < KPAD; n += 256)
        atomicAdd(&outSlab[n],
                  cols4[0][n] + cols4[1][n] + cols4[2][n] + cols4[3][n]);
}

// ---------------------------------------------------------------------------
// out: prologue folds 8-slab reduce of S2 (float4); out[b,:] = E[b,:]*r / rowsum.
// 1024 blocks, 1 row per wave, rows < 4096.
__global__ __launch_bounds__(256)
void out_k(const f16* __restrict__ E16, const float* __restrict__ S2sl,
           float* __restrict__ out) {
    __shared__ float rl[KPAD];
    int tid = threadIdx.x;
    {
        int n = tid * 4;
        float4 s = *(const float4*)(S2sl + n);
#pragma unroll
        for (int j = 1; j < NSLAB; ++j) {
            float4 t = *(const float4*)(S2sl + (size_t)j * KPAD + n);
            s.x += t.x; s.y += t.y; s.z += t.z; s.w += t.w;
        }
        float4 o;
        o.x = (n + 0 < KDIM) ? 1.0f / (1000.0f * s.x) : 0.0f;
        o.y = (n + 1 < KDIM) ? 1.0f / (1000.0f * s.y) : 0.0f;
        o.z = (n + 2 < KDIM) ? 1.0f / (1000.0f * s.z) : 0.0f;
        o.w = (n + 3 < KDIM) ? 1.0f / (1000.0f * s.w) : 0.0f;
        *(float4*)(rl + n) = o;
    }
    __syncthreads();
    int wave = tid >> 6, lane = tid & 63;
    int n0 = lane * 16;
    float rv[16];
#pragma unroll
    for (int i = 0; i < 16; ++i) rv[i] = rl[n0 + i];
    int row = blockIdx.x * 4 + wave;
    const f16* er = E16 + (size_t)row * KPAD + n0;
    f16x8 e0 = *(const f16x8*)er;
    f16x8 e1 = *(const f16x8*)(er + 8);
    float w[16];
    float p = 0.f;
#pragma unroll
    for (int i = 0; i < 8; ++i) {
        w[i] = (float)e0[i] * rv[i];
        w[8 + i] = (float)e1[i] * rv[8 + i];
    }
#pragma unroll
    for (int i = 0; i < 16; ++i) p += w[i];
    p = wsum(p);
    float inv = 1.0f / p;
    float* orow = out + (size_t)row * KDIM;
#pragma unroll
    for (int i = 0; i < 16; i += 4) {
        int n = n0 + i;
        if (n + 3 < KDIM) {
            float4 o = { w[i] * inv, w[i + 1] * inv, w[i + 2] * inv, w[i + 3] * inv };
            *(float4*)(orow + n) = o;
        } else {
#pragma unroll
            for (int t = 0; t < 4; ++t)
                if (n + t < KDIM) orow[n + t] = w[i + t] * inv;
        }
    }
}

// ---------------------------------------------------------------------------
extern "C" void kernel_launch(void* const* d_in, const int* in_sizes, int n_in,
                              void* d_out, int out_size, void* d_ws, size_t ws_size,
                              hipStream_t stream) {
    (void)in_sizes; (void)n_in; (void)out_size; (void)ws_size;
    const float* feats = (const float*)d_in[0];   // [4096,256]
    const float* head  = (const float*)d_in[1];   // [256,1000]
    const float* queue = (const float*)d_in[2];   // [8192,256]
    float* out = (float*)d_out;                   // [4096,1000]

    char* ws = (char*)d_ws;
    f16*   A16   = (f16*)(ws + OFF_A16);
    f16*   Bf    = (f16*)(ws + OFF_BF);
    f16*   E16   = (f16*)(ws + OFF_E16);
    float* slabs = (float*)(ws + OFF_SL);
    float* S0sl  = slabs;
    float* S1sl  = slabs + NSLAB * KPAD;
    float* S2sl  = slabs + 2 * NSLAB * KPAD;

    prep_k<<<3128, 256, 0, stream>>>(feats, queue, head, A16, Bf, slabs);
    gemm_exp_k<<<dim3(8, 96), 256, 0, stream>>>(A16, Bf, E16, S0sl);
    rowpass_k<<<768, 256, 0, stream>>>(E16, S0sl, S1sl);
    rowpass_k<<<768, 256, 0, stream>>>(E16, S1sl, S2sl);
    out_k<<<NFEAT / 4, 256, 0, stream>>>(E16, S2sl, out);
}